// Round 1
// baseline (400.300 us; speedup 1.0000x reference)
//
#include <hip/hip_runtime.h>
#include <math.h>

#define NTOK 1024
#define ROWS 8

// B=4, DIM=256, NH=8, HEAD_DIM=32, KEY_DIM=16, QKV_OUT=512, SCALE=0.25
__device__ __forceinline__ unsigned int f2key(float f) {
  unsigned int u = __float_as_uint(f);
  return (u & 0x80000000u) ? ~u : (u | 0x80000000u);
}
__device__ __forceinline__ float key2f(unsigned int u) {
  return (u & 0x80000000u) ? __uint_as_float(u ^ 0x80000000u) : __uint_as_float(~u);
}

// Generic conv1x1 / GEMM: out[b,oc,p] = bias[oc] + sum_c w[oc,c]*in[b,c,p]
// grid = B * (OC/8) * (NTOK/256), block = 256. 8 out-channels per thread.
template<int OC, bool RELU>
__global__ __launch_bounds__(256) void conv1x1_kernel(const float* __restrict__ in,
    const float* __restrict__ w, const float* __restrict__ bias, float* __restrict__ out) {
  __shared__ float wsm[256][8];
  int bid = blockIdx.x;
  const int pb = bid & 3; bid >>= 2;
  const int ocb = bid % (OC / 8); const int b = bid / (OC / 8);
  const int tid = threadIdx.x;
  for (int i = tid; i < 2048; i += 256) {
    int j = i >> 8, c = i & 255;
    wsm[c][j] = w[(size_t)(ocb * 8 + j) * 256 + c];
  }
  __syncthreads();
  const int p = pb * 256 + tid;
  const float* inb = in + (size_t)b * 256 * NTOK + p;
  float acc[8];
  #pragma unroll
  for (int j = 0; j < 8; j++) acc[j] = bias[ocb * 8 + j];
  #pragma unroll 4
  for (int c = 0; c < 256; c++) {
    float xv = inb[(size_t)c * NTOK];
    const float4 wa = *(const float4*)&wsm[c][0];
    const float4 wb = *(const float4*)&wsm[c][4];
    acc[0] = fmaf(wa.x, xv, acc[0]);
    acc[1] = fmaf(wa.y, xv, acc[1]);
    acc[2] = fmaf(wa.z, xv, acc[2]);
    acc[3] = fmaf(wa.w, xv, acc[3]);
    acc[4] = fmaf(wb.x, xv, acc[4]);
    acc[5] = fmaf(wb.y, xv, acc[5]);
    acc[6] = fmaf(wb.z, xv, acc[6]);
    acc[7] = fmaf(wb.w, xv, acc[7]);
  }
  #pragma unroll
  for (int j = 0; j < 8; j++) {
    float v = acc[j];
    if (RELU) v = fmaxf(v, 0.f);
    out[((size_t)b * OC + ocb * 8 + j) * NTOK + p] = v;
  }
}

// g2 = sigmoid(g2_w . relu_g1 + g2_b), deterministic fp64 block partial sums
__global__ __launch_bounds__(256) void gate2_kernel(const float* __restrict__ gx,
    const float* __restrict__ g2_w, const float* __restrict__ g2_b, double* __restrict__ part) {
  const int idx = blockIdx.x * 256 + threadIdx.x;
  const int b = idx >> 10, p = idx & 1023;
  float acc = g2_b[0];
  const float* gb = gx + (size_t)b * 128 * NTOK + p;
  #pragma unroll 4
  for (int j = 0; j < 128; j++) acc = fmaf(g2_w[j], gb[(size_t)j * NTOK], acc);
  float g = 1.f / (1.f + expf(-acc));
  __shared__ double red[256];
  red[threadIdx.x] = (double)g;
  __syncthreads();
  for (int s = 128; s > 0; s >>= 1) {
    if (threadIdx.x < s) red[threadIdx.x] += red[threadIdx.x + s];
    __syncthreads();
  }
  if (threadIdx.x == 0) part[blockIdx.x] = red[0];
}

__global__ void dynk_kernel(const double* __restrict__ part, int* __restrict__ dynk) {
  double s = 0.0;
  for (int i = 0; i < 16; i++) s += part[i];
  double mean = s / 4096.0;
  int k = (int)floor(1024.0 * mean);
  if (k < 1) k = 1;
  if (k > NTOK) k = NTOK;
  *dynk = k;
}

// Attention: one block per 8 query rows of one (b,h).
// Logits in LDS (fp32) -> exact top-dyn_k (radix bin + candidate ranking,
// ties broken by smaller index, matching stable argsort) -> softmax -> PV.
__global__ __launch_bounds__(256) void attn_kernel(const float* __restrict__ qkv,
    const int* __restrict__ dynk_p, float* __restrict__ out_attn) {
  const int tid = threadIdx.x;
  const int lane = tid & 63, wv = tid >> 6;
  int bid = blockIdx.x;
  const int mb = bid & 127; bid >>= 7;
  const int h = bid & 7; const int b = bid >> 3;
  int dk = *dynk_p;
  const int dyn_k = dk < 1 ? 1 : (dk > NTOK ? NTOK : dk);
  const float* base = qkv + (size_t)(b * 512 + h * 64) * NTOK;

  __shared__ float sm[ROWS][NTOK];       // logits -> exp weights
  __shared__ float qs[16][ROWS];
  __shared__ float invsum[ROWS];
  __shared__ unsigned int wredU[4];
  __shared__ float wredF[4];
  __shared__ int ibin, icga, candcnt, needed_sh, ce_sh;
  __shared__ unsigned int T_sh;
  __shared__ union UU {
    struct { int hist[256]; int wtot[4]; unsigned int cand[NTOK]; } s;
    float red[ROWS][8][32];
  } u;

  if (tid < 16 * ROWS)
    qs[tid >> 3][tid & 7] = base[(size_t)(tid >> 3) * NTOK + mb * ROWS + (tid & 7)];
  __syncthreads();

  // ---- logits: each thread computes n = 4*tid..4*tid+3 for all 8 rows ----
  {
    const float4* k4 = (const float4*)(base + 16 * NTOK);
    float acc[ROWS][4];
    #pragma unroll
    for (int r = 0; r < ROWS; r++) { acc[r][0] = acc[r][1] = acc[r][2] = acc[r][3] = 0.f; }
    #pragma unroll
    for (int d = 0; d < 16; d++) {
      float4 kk = k4[d * 256 + tid];
      #pragma unroll
      for (int r = 0; r < ROWS; r++) {
        float qv = qs[d][r];
        acc[r][0] = fmaf(qv, kk.x, acc[r][0]);
        acc[r][1] = fmaf(qv, kk.y, acc[r][1]);
        acc[r][2] = fmaf(qv, kk.z, acc[r][2]);
        acc[r][3] = fmaf(qv, kk.w, acc[r][3]);
      }
    }
    #pragma unroll
    for (int r = 0; r < ROWS; r++)
      ((float4*)sm[r])[tid] = make_float4(acc[r][0] * 0.25f, acc[r][1] * 0.25f,
                                          acc[r][2] * 0.25f, acc[r][3] * 0.25f);
  }
  __syncthreads();

  // ---- per-row top-k + softmax ----
  for (int r = 0; r < ROWS; r++) {
    float4 f4 = ((const float4*)sm[r])[tid];
    float fv[4] = {f4.x, f4.y, f4.z, f4.w};
    unsigned int key[4];
    #pragma unroll
    for (int i = 0; i < 4; i++) key[i] = f2key(fv[i]);

    unsigned int T = 0u;
    bool keepAllEq = true;
    int eqk[4] = {1, 1, 1, 1};
    if (dyn_k < NTOK) {
      u.s.hist[tid] = 0;
      if (tid == 0) candcnt = 0;
      __syncthreads();
      #pragma unroll
      for (int i = 0; i < 4; i++) atomicAdd(&u.s.hist[key[i] >> 24], 1);
      __syncthreads();
      // inclusive suffix-sum over 256 bins (bin tid): cum = #keys with byte >= tid
      int v = u.s.hist[tid];
      #pragma unroll
      for (int off = 1; off < 64; off <<= 1) {
        int o = __shfl_down(v, off);
        if (lane + off < 64) v += o;
      }
      if (lane == 0) u.s.wtot[wv] = v;
      __syncthreads();
      int add = 0;
      for (int w2 = wv + 1; w2 < 4; w2++) add += u.s.wtot[w2];
      v += add;
      int cumNext = __shfl_down(v, 1);
      if (lane == 63) cumNext = add;
      if (v >= dyn_k && cumNext < dyn_k) { ibin = tid; icga = cumNext; }
      __syncthreads();
      const int bin = ibin;
      const int kc2 = dyn_k - icga;   // # to keep among byte==bin
      #pragma unroll
      for (int i = 0; i < 4; i++)
        if ((int)(key[i] >> 24) == bin) {
          int ix = atomicAdd(&candcnt, 1);
          u.s.cand[ix] = key[i];
        }
      __syncthreads();
      const int m = candcnt;
      for (int ii = tid; ii < m; ii += 256) {
        unsigned int mykey = u.s.cand[ii];
        int cg = 0, ce = 0;
        for (int j = 0; j < m; j++) {
          unsigned int kj = u.s.cand[j];
          cg += (kj > mykey) ? 1 : 0;
          ce += (kj == mykey) ? 1 : 0;
        }
        if (cg < kc2 && cg + ce >= kc2) { T_sh = mykey; needed_sh = kc2 - cg; ce_sh = ce; }
      }
      __syncthreads();
      T = T_sh;
      const int needed = needed_sh;
      keepAllEq = (needed >= ce_sh);
      if (!keepAllEq) {
        // rank equals by index (stable-sort tie rule): exclusive scan of counts
        int loc = 0, le[4];
        #pragma unroll
        for (int i = 0; i < 4; i++) { le[i] = loc; loc += (key[i] == T) ? 1 : 0; }
        int sv = loc;
        #pragma unroll
        for (int off = 1; off < 64; off <<= 1) {
          int o = __shfl_up(sv, off);
          if (lane >= off) sv += o;
        }
        if (lane == 63) u.s.wtot[wv] = sv;
        __syncthreads();
        int bse = 0;
        for (int w2 = 0; w2 < wv; w2++) bse += u.s.wtot[w2];
        int excl = bse + sv - loc;
        #pragma unroll
        for (int i = 0; i < 4; i++) eqk[i] = (excl + le[i] < needed) ? 1 : 0;
        __syncthreads();
      }
    }
    // row max (global max == kept max since dyn_k >= 1)
    unsigned int mk = key[0];
    mk = key[1] > mk ? key[1] : mk;
    mk = key[2] > mk ? key[2] : mk;
    mk = key[3] > mk ? key[3] : mk;
    #pragma unroll
    for (int off = 1; off < 64; off <<= 1) {
      unsigned int o = __shfl_xor(mk, off);
      mk = o > mk ? o : mk;
    }
    if (lane == 0) wredU[wv] = mk;
    __syncthreads();
    {
      unsigned int m0 = wredU[0], m1 = wredU[1], m2 = wredU[2], m3 = wredU[3];
      unsigned int ma = m0 > m1 ? m0 : m1, mb2 = m2 > m3 ? m2 : m3;
      mk = ma > mb2 ? ma : mb2;
    }
    const float mx = key2f(mk);
    float rs = 0.f, e[4];
    #pragma unroll
    for (int i = 0; i < 4; i++) {
      bool keep;
      if (dyn_k >= NTOK) keep = true;
      else keep = (key[i] > T) || (key[i] == T && (keepAllEq || (eqk[i] != 0)));
      e[i] = keep ? __expf(fv[i] - mx) : 0.f;
      rs += e[i];
    }
    ((float4*)sm[r])[tid] = make_float4(e[0], e[1], e[2], e[3]);
    #pragma unroll
    for (int off = 1; off < 64; off <<= 1) rs += __shfl_xor(rs, off);
    __syncthreads();
    if (lane == 0) wredF[wv] = rs;
    __syncthreads();
    if (tid == 0) invsum[r] = 1.f / (wredF[0] + wredF[1] + wredF[2] + wredF[3]);
  }
  __syncthreads();

  // ---- PV: out[d,m] = invsum * sum_n e[m,n] v[d,n]; v read once per block ----
  {
    const float4* v4 = (const float4*)(base + 32 * NTOK);
    const int d = tid & 31, s = tid >> 5;
    float acc[ROWS];
    #pragma unroll
    for (int r = 0; r < ROWS; r++) acc[r] = 0.f;
    for (int jj = 0; jj < 32; jj++) {
      float4 vv = v4[(size_t)d * 256 + s * 32 + jj];
      #pragma unroll
      for (int r = 0; r < ROWS; r++) {
        float4 pp = ((const float4*)sm[r])[s * 32 + jj];
        acc[r] = fmaf(pp.x, vv.x, acc[r]);
        acc[r] = fmaf(pp.y, vv.y, acc[r]);
        acc[r] = fmaf(pp.z, vv.z, acc[r]);
        acc[r] = fmaf(pp.w, vv.w, acc[r]);
      }
    }
    __syncthreads();
    #pragma unroll
    for (int r = 0; r < ROWS; r++) u.red[r][s][d] = acc[r];
    __syncthreads();
    const int r2 = tid >> 5, d2 = tid & 31;
    float sum = 0.f;
    #pragma unroll
    for (int s2 = 0; s2 < 8; s2++) sum += u.red[r2][s2][d2];
    sum *= invsum[r2];
    out_attn[((size_t)(b * 256 + h * 32 + d2)) * NTOK + mb * ROWS + r2] = sum;
  }
}

// depthwise 3x3 conv on v image + bias, fused add of attention output
__global__ __launch_bounds__(256) void pe_kernel(const float* __restrict__ qkv,
    const float* __restrict__ oattn, const float* __restrict__ pe_w,
    const float* __restrict__ pe_b, float* __restrict__ tmp) {
  int bid = blockIdx.x;
  const int c = bid & 255; const int b = bid >> 8;
  const int oc = ((c >> 5) * 64) + 32 + (c & 31);   // v channel within qkv layout
  const float* vimg = qkv + (size_t)(b * 512 + oc) * NTOK;
  float wloc[9];
  #pragma unroll
  for (int i = 0; i < 9; i++) wloc[i] = pe_w[c * 9 + i];
  const float bv = pe_b[c];
  const float* oa = oattn + (size_t)(b * 256 + c) * NTOK;
  float* tp = tmp + (size_t)(b * 256 + c) * NTOK;
  for (int p = threadIdx.x; p < NTOK; p += 256) {
    const int y = p >> 5, x = p & 31;
    float s = bv;
    #pragma unroll
    for (int dy = -1; dy <= 1; dy++) {
      int yy = y + dy;
      if (yy < 0 || yy > 31) continue;
      #pragma unroll
      for (int dx = -1; dx <= 1; dx++) {
        int xx = x + dx;
        if (xx < 0 || xx > 31) continue;
        s = fmaf(wloc[(dy + 1) * 3 + (dx + 1)], vimg[yy * 32 + xx], s);
      }
    }
    tp[p] = s + oa[p];
  }
}

extern "C" void kernel_launch(void* const* d_in, const int* in_sizes, int n_in,
                              void* d_out, int out_size, void* d_ws, size_t ws_size,
                              hipStream_t stream) {
  const float* x      = (const float*)d_in[0];
  const float* qkv_w  = (const float*)d_in[1];
  const float* qkv_b  = (const float*)d_in[2];
  const float* proj_w = (const float*)d_in[3];
  const float* proj_b = (const float*)d_in[4];
  const float* pe_w   = (const float*)d_in[5];
  const float* pe_b   = (const float*)d_in[6];
  const float* g1_w   = (const float*)d_in[7];
  const float* g1_b   = (const float*)d_in[8];
  const float* g2_w   = (const float*)d_in[9];
  const float* g2_b   = (const float*)d_in[10];
  float* out = (float*)d_out;

  char* ws = (char*)d_ws;
  float*  qkvb  = (float*)(ws);                          // B*512*1024*4 = 8 MB
  float*  oattn = (float*)(ws + (8u << 20));             // 4 MB
  float*  tmp   = (float*)(ws + (12u << 20));            // 4 MB
  float*  gx    = (float*)(ws + (16u << 20));            // B*128*1024*4 = 2 MB
  double* part  = (double*)(ws + (18u << 20));           // 16 doubles
  int*    dynk  = (int*)(ws + (18u << 20) + 256);

  // gate path -> dyn_k (deterministic)
  conv1x1_kernel<128, true><<<256, 256, 0, stream>>>(x, g1_w, g1_b, gx);
  gate2_kernel<<<16, 256, 0, stream>>>(gx, g2_w, g2_b, part);
  dynk_kernel<<<1, 1, 0, stream>>>(part, dynk);
  // qkv
  conv1x1_kernel<512, false><<<1024, 256, 0, stream>>>(x, qkv_w, qkv_b, qkvb);
  // attention with exact top-dyn_k masked softmax
  attn_kernel<<<4096, 256, 0, stream>>>(qkvb, dynk, oattn);
  // depthwise PE conv + add
  pe_kernel<<<1024, 256, 0, stream>>>(qkvb, oattn, pe_w, pe_b, tmp);
  // final projection
  conv1x1_kernel<256, false><<<512, 256, 0, stream>>>(tmp, proj_w, proj_b, out);
}

// Round 2
// 336.158 us; speedup vs baseline: 1.1908x; 1.1908x over previous
//
#include <hip/hip_runtime.h>
#include <math.h>

#define NTOK 1024
#define CAP 160

#define LDS_FENCE() asm volatile("s_waitcnt lgkmcnt(0)" ::: "memory")

// B=4, DIM=256, NH=8, HEAD_DIM=32, KEY_DIM=16, QKV_OUT=512, SCALE=0.25

// Generic conv1x1 / GEMM: out[b,oc,p] = bias[oc] + sum_c w[oc,c]*in[b,c,p]
// grid = B * (OC/8) * (NTOK/256), block = 256. 8 out-channels per thread.
template<int OC, bool RELU>
__global__ __launch_bounds__(256) void conv1x1_kernel(const float* __restrict__ in,
    const float* __restrict__ w, const float* __restrict__ bias, float* __restrict__ out) {
  __shared__ float wsm[256][8];
  int bid = blockIdx.x;
  const int pb = bid & 3; bid >>= 2;
  const int ocb = bid % (OC / 8); const int b = bid / (OC / 8);
  const int tid = threadIdx.x;
  for (int i = tid; i < 2048; i += 256) {
    int j = i >> 8, c = i & 255;
    wsm[c][j] = w[(size_t)(ocb * 8 + j) * 256 + c];
  }
  __syncthreads();
  const int p = pb * 256 + tid;
  const float* inb = in + (size_t)b * 256 * NTOK + p;
  float acc[8];
  #pragma unroll
  for (int j = 0; j < 8; j++) acc[j] = bias[ocb * 8 + j];
  #pragma unroll 4
  for (int c = 0; c < 256; c++) {
    float xv = inb[(size_t)c * NTOK];
    const float4 wa = *(const float4*)&wsm[c][0];
    const float4 wb = *(const float4*)&wsm[c][4];
    acc[0] = fmaf(wa.x, xv, acc[0]);
    acc[1] = fmaf(wa.y, xv, acc[1]);
    acc[2] = fmaf(wa.z, xv, acc[2]);
    acc[3] = fmaf(wa.w, xv, acc[3]);
    acc[4] = fmaf(wb.x, xv, acc[4]);
    acc[5] = fmaf(wb.y, xv, acc[5]);
    acc[6] = fmaf(wb.z, xv, acc[6]);
    acc[7] = fmaf(wb.w, xv, acc[7]);
  }
  #pragma unroll
  for (int j = 0; j < 8; j++) {
    float v = acc[j];
    if (RELU) v = fmaxf(v, 0.f);
    out[((size_t)b * OC + ocb * 8 + j) * NTOK + p] = v;
  }
}

// g2 = sigmoid(g2_w . relu_g1 + g2_b), deterministic fp64 block partial sums
__global__ __launch_bounds__(256) void gate2_kernel(const float* __restrict__ gx,
    const float* __restrict__ g2_w, const float* __restrict__ g2_b, double* __restrict__ part) {
  const int idx = blockIdx.x * 256 + threadIdx.x;
  const int b = idx >> 10, p = idx & 1023;
  float acc = g2_b[0];
  const float* gb = gx + (size_t)b * 128 * NTOK + p;
  #pragma unroll 4
  for (int j = 0; j < 128; j++) acc = fmaf(g2_w[j], gb[(size_t)j * NTOK], acc);
  float g = 1.f / (1.f + expf(-acc));
  __shared__ double red[256];
  red[threadIdx.x] = (double)g;
  __syncthreads();
  for (int s = 128; s > 0; s >>= 1) {
    if (threadIdx.x < s) red[threadIdx.x] += red[threadIdx.x + s];
    __syncthreads();
  }
  if (threadIdx.x == 0) part[blockIdx.x] = red[0];
}

__global__ void dynk_kernel(const double* __restrict__ part, int* __restrict__ dynk) {
  double s = 0.0;
  for (int i = 0; i < 16; i++) s += part[i];
  double mean = s / 4096.0;
  int k = (int)floor(1024.0 * mean);
  if (k < 1) k = 1;
  if (k > NTOK) k = NTOK;
  *dynk = k;
}

// Attention: one block = 8 query rows of one (b,h). Selection is WAVE-LOCAL:
// each of the 4 waves owns 2 rows; top-dyn_k via 2-level 64-bin value-range
// radix refine -> exact boundary element B=(value,index) -> per-element keep
// predicate (v > Bv) || (v == Bv && n <= Bn)  (stable-argsort tie rule).
__global__ __launch_bounds__(256) void attn_kernel(const float* __restrict__ qkv,
    const int* __restrict__ dynk_p, float* __restrict__ out_attn) {
  const int tid = threadIdx.x;
  const int lane = tid & 63, wv = tid >> 6;
  int bid = blockIdx.x;
  const int mb = bid & 127; bid >>= 7;
  const int h = bid & 7; const int b = bid >> 3;
  int dk = *dynk_p;
  const int dyn_k = dk < 1 ? 1 : (dk > NTOK ? NTOK : dk);
  const float* base = qkv + (size_t)(b * 512 + h * 64) * NTOK;

  __shared__ float sm[8][1028];   // padded: +4 floats/row kills PV bank conflict
  __shared__ float invs[8];
  __shared__ union UU {
    float qs[16][8];
    struct {
      int hist[4][64];
      int cnt[4];
      float Bv[4]; int Bn[4];
      struct { float v; int n; } cand[4][CAP];
    } sel;
  } u;

  if (tid < 128)
    u.qs[tid >> 3][tid & 7] = base[(size_t)(tid >> 3) * NTOK + mb * 8 + (tid & 7)];
  __syncthreads();

  // ---- logits: thread computes n = 4*tid..4*tid+3 for all 8 rows ----
  {
    const float4* k4 = (const float4*)(base + 16 * NTOK);
    float acc[8][4];
    #pragma unroll
    for (int r = 0; r < 8; r++) { acc[r][0] = acc[r][1] = acc[r][2] = acc[r][3] = 0.f; }
    #pragma unroll
    for (int d = 0; d < 16; d++) {
      float4 kk = k4[d * 256 + tid];
      #pragma unroll
      for (int r = 0; r < 8; r++) {
        float qv = u.qs[d][r];
        acc[r][0] = fmaf(qv, kk.x, acc[r][0]);
        acc[r][1] = fmaf(qv, kk.y, acc[r][1]);
        acc[r][2] = fmaf(qv, kk.z, acc[r][2]);
        acc[r][3] = fmaf(qv, kk.w, acc[r][3]);
      }
    }
    #pragma unroll
    for (int r = 0; r < 8; r++)
      ((float4*)&sm[r][0])[tid] = make_float4(acc[r][0] * 0.25f, acc[r][1] * 0.25f,
                                              acc[r][2] * 0.25f, acc[r][3] * 0.25f);
  }
  __syncthreads();   // logits ready; qs dead -> sel region live

  // ---- wave-local selection + softmax: wave wv owns rows 2*wv, 2*wv+1 ----
  for (int rr = 0; rr < 2; rr++) {
    const int r = wv * 2 + rr;
    float* smrow = &sm[r][0];
    float v[16];
    {
      float4 f0 = ((const float4*)smrow)[lane];
      float4 f1 = ((const float4*)smrow)[64 + lane];
      float4 f2 = ((const float4*)smrow)[128 + lane];
      float4 f3 = ((const float4*)smrow)[192 + lane];
      v[0]=f0.x; v[1]=f0.y; v[2]=f0.z; v[3]=f0.w;
      v[4]=f1.x; v[5]=f1.y; v[6]=f1.z; v[7]=f1.w;
      v[8]=f2.x; v[9]=f2.y; v[10]=f2.z; v[11]=f2.w;
      v[12]=f3.x; v[13]=f3.y; v[14]=f3.z; v[15]=f3.w;
    }
    // element (j,i) has token index n = j*256 + lane*4 + i, j = i>>2? no: j=idx/4
    float mn = v[0], mx = v[0];
    #pragma unroll
    for (int i = 1; i < 16; i++) { mn = fminf(mn, v[i]); mx = fmaxf(mx, v[i]); }
    #pragma unroll
    for (int off = 32; off > 0; off >>= 1) {
      mn = fminf(mn, __shfl_xor(mn, off));
      mx = fmaxf(mx, __shfl_xor(mx, off));
    }

    unsigned int keepmask = 0xFFFFu;
    if (dyn_k < NTOK) {
      float Bv = mx; int Bn = dyn_k - 1;        // degenerate (all-equal) default
      const float range = mx - mn;
      const bool fine = (range > 0.f);
      int m = 0;
      if (fine) {
        const float s1 = 64.0f / range;
        // pass 1: 64 bins over [mn,mx]
        u.sel.hist[wv][lane] = 0;
        LDS_FENCE();
        int idx1[16];
        #pragma unroll
        for (int i = 0; i < 16; i++) {
          int ix = (int)((v[i] - mn) * s1);
          ix = ix < 0 ? 0 : (ix > 63 ? 63 : ix);
          idx1[i] = ix;
          atomicAdd(&u.sel.hist[wv][ix], 1);
        }
        LDS_FENCE();
        int cum = u.sel.hist[wv][lane];
        #pragma unroll
        for (int off = 1; off < 64; off <<= 1) {
          int o = __shfl_down(cum, off);
          if (lane + off < 64) cum += o;
        }
        int cumNext = __shfl_down(cum, 1);
        if (lane == 63) cumNext = 0;
        unsigned long long bal = __ballot(cum >= dyn_k && cumNext < dyn_k);
        const int t = (int)__builtin_ctzll(bal);
        const int k2 = dyn_k - __shfl(cumNext, t);
        // pass 2: 64 sub-bins within bin t
        const float binw = range * (1.0f / 64.0f);
        const float lo = mn + (float)t * binw;
        float s2 = 4096.0f / range;
        if (!(s2 < 3.0e38f)) s2 = 0.f;
        u.sel.hist[wv][lane] = 0;
        LDS_FENCE();
        #pragma unroll
        for (int i = 0; i < 16; i++) {
          if (idx1[i] == t) {
            int ix = (int)((v[i] - lo) * s2);
            ix = ix < 0 ? 0 : (ix > 63 ? 63 : ix);
            atomicAdd(&u.sel.hist[wv][ix], 1);
          }
        }
        LDS_FENCE();
        cum = u.sel.hist[wv][lane];
        #pragma unroll
        for (int off = 1; off < 64; off <<= 1) {
          int o = __shfl_down(cum, off);
          if (lane + off < 64) cum += o;
        }
        cumNext = __shfl_down(cum, 1);
        if (lane == 63) cumNext = 0;
        bal = __ballot(cum >= k2 && cumNext < k2);
        const int t2 = (int)__builtin_ctzll(bal);
        const int k3 = k2 - __shfl(cumNext, t2);
        // collect candidates in sub-bin (t,t2)
        if (lane == 0) u.sel.cnt[wv] = 0;
        LDS_FENCE();
        #pragma unroll
        for (int i = 0; i < 16; i++) {
          if (idx1[i] == t) {
            int ix = (int)((v[i] - lo) * s2);
            ix = ix < 0 ? 0 : (ix > 63 ? 63 : ix);
            if (ix == t2) {
              int p = atomicAdd(&u.sel.cnt[wv], 1);
              if (p < CAP) { u.sel.cand[wv][p].v = v[i]; u.sel.cand[wv][p].n = (i >> 2) * 256 + lane * 4 + (i & 3); }
            }
          }
        }
        LDS_FENCE();
        m = u.sel.cnt[wv];
        if (m <= CAP) {
          // exact boundary element: rank k3-1 among candidates (value desc, idx asc)
          for (int ii = lane; ii < m; ii += 64) {
            float cv = u.sel.cand[wv][ii].v; int cn = u.sel.cand[wv][ii].n;
            int rk = 0;
            for (int j = 0; j < m; j++) {
              float ov = u.sel.cand[wv][j].v; int on = u.sel.cand[wv][j].n;
              rk += ((ov > cv) || (ov == cv && on < cn)) ? 1 : 0;
            }
            if (rk == k3 - 1) { u.sel.Bv[wv] = cv; u.sel.Bn[wv] = cn; }
          }
          LDS_FENCE();
          Bv = u.sel.Bv[wv]; Bn = u.sel.Bn[wv];
        }
      }
      if (fine && m > CAP) {
        // exact fallback: brute-force rank vs whole row (never on smooth data)
        keepmask = 0u;
        #pragma unroll
        for (int i = 0; i < 16; i++) {
          const int n_i = (i >> 2) * 256 + lane * 4 + (i & 3);
          const float vi = v[i];
          int rk = 0;
          for (int j = 0; j < NTOK; j++) {
            float ov = smrow[j];
            rk += ((ov > vi) || (ov == vi && j < n_i)) ? 1 : 0;
          }
          if (rk < dyn_k) keepmask |= (1u << i);
        }
      } else {
        keepmask = 0u;
        #pragma unroll
        for (int i = 0; i < 16; i++) {
          const int n_i = (i >> 2) * 256 + lane * 4 + (i & 3);
          if ((v[i] > Bv) || (v[i] == Bv && n_i <= Bn)) keepmask |= (1u << i);
        }
      }
    }
    // softmax (row max mx is always kept: rank 0 < dyn_k)
    float e[16]; float s = 0.f;
    #pragma unroll
    for (int i = 0; i < 16; i++) {
      e[i] = ((keepmask >> i) & 1u) ? __expf(v[i] - mx) : 0.f;
      s += e[i];
    }
    #pragma unroll
    for (int off = 32; off > 0; off >>= 1) s += __shfl_xor(s, off);
    if (lane == 0) invs[r] = 1.f / s;
    ((float4*)smrow)[lane]       = make_float4(e[0], e[1], e[2], e[3]);
    ((float4*)smrow)[64 + lane]  = make_float4(e[4], e[5], e[6], e[7]);
    ((float4*)smrow)[128 + lane] = make_float4(e[8], e[9], e[10], e[11]);
    ((float4*)smrow)[192 + lane] = make_float4(e[12], e[13], e[14], e[15]);
  }
  __syncthreads();

  // ---- PV: thread (r,d) computes full sum over n; no reduction buffer ----
  {
    const int r2 = tid & 7, d2 = tid >> 3;
    const float4* v4 = (const float4*)(base + (size_t)(32 + d2) * NTOK);
    const float4* p4 = (const float4*)&sm[r2][0];
    float acc = 0.f;
    #pragma unroll 4
    for (int n4 = 0; n4 < 256; n4++) {
      float4 vv = v4[n4];
      float4 pp = p4[n4];
      acc = fmaf(pp.x, vv.x, acc);
      acc = fmaf(pp.y, vv.y, acc);
      acc = fmaf(pp.z, vv.z, acc);
      acc = fmaf(pp.w, vv.w, acc);
    }
    acc *= invs[r2];
    out_attn[(size_t)(b * 256 + h * 32 + d2) * NTOK + mb * 8 + r2] = acc;
  }
}

// depthwise 3x3 conv on v image + bias, fused add of attention output
__global__ __launch_bounds__(256) void pe_kernel(const float* __restrict__ qkv,
    const float* __restrict__ oattn, const float* __restrict__ pe_w,
    const float* __restrict__ pe_b, float* __restrict__ tmp) {
  int bid = blockIdx.x;
  const int c = bid & 255; const int b = bid >> 8;
  const int oc = ((c >> 5) * 64) + 32 + (c & 31);   // v channel within qkv layout
  const float* vimg = qkv + (size_t)(b * 512 + oc) * NTOK;
  float wloc[9];
  #pragma unroll
  for (int i = 0; i < 9; i++) wloc[i] = pe_w[c * 9 + i];
  const float bv = pe_b[c];
  const float* oa = oattn + (size_t)(b * 256 + c) * NTOK;
  float* tp = tmp + (size_t)(b * 256 + c) * NTOK;
  for (int p = threadIdx.x; p < NTOK; p += 256) {
    const int y = p >> 5, x = p & 31;
    float s = bv;
    #pragma unroll
    for (int dy = -1; dy <= 1; dy++) {
      int yy = y + dy;
      if (yy < 0 || yy > 31) continue;
      #pragma unroll
      for (int dx = -1; dx <= 1; dx++) {
        int xx = x + dx;
        if (xx < 0 || xx > 31) continue;
        s = fmaf(wloc[(dy + 1) * 3 + (dx + 1)], vimg[yy * 32 + xx], s);
      }
    }
    tp[p] = s + oa[p];
  }
}

extern "C" void kernel_launch(void* const* d_in, const int* in_sizes, int n_in,
                              void* d_out, int out_size, void* d_ws, size_t ws_size,
                              hipStream_t stream) {
  const float* x      = (const float*)d_in[0];
  const float* qkv_w  = (const float*)d_in[1];
  const float* qkv_b  = (const float*)d_in[2];
  const float* proj_w = (const float*)d_in[3];
  const float* proj_b = (const float*)d_in[4];
  const float* pe_w   = (const float*)d_in[5];
  const float* pe_b   = (const float*)d_in[6];
  const float* g1_w   = (const float*)d_in[7];
  const float* g1_b   = (const float*)d_in[8];
  const float* g2_w   = (const float*)d_in[9];
  const float* g2_b   = (const float*)d_in[10];
  float* out = (float*)d_out;

  char* ws = (char*)d_ws;
  float*  qkvb  = (float*)(ws);                          // B*512*1024*4 = 8 MB
  float*  oattn = (float*)(ws + (8u << 20));             // 4 MB
  float*  tmp   = (float*)(ws + (12u << 20));            // 4 MB
  float*  gx    = (float*)(ws + (16u << 20));            // B*128*1024*4 = 2 MB
  double* part  = (double*)(ws + (18u << 20));           // 16 doubles
  int*    dynk  = (int*)(ws + (18u << 20) + 256);

  // gate path -> dyn_k (deterministic)
  conv1x1_kernel<128, true><<<256, 256, 0, stream>>>(x, g1_w, g1_b, gx);
  gate2_kernel<<<16, 256, 0, stream>>>(gx, g2_w, g2_b, part);
  dynk_kernel<<<1, 1, 0, stream>>>(part, dynk);
  // qkv
  conv1x1_kernel<512, false><<<1024, 256, 0, stream>>>(x, qkv_w, qkv_b, qkvb);
  // attention with exact top-dyn_k masked softmax
  attn_kernel<<<4096, 256, 0, stream>>>(qkvb, dynk, oattn);
  // depthwise PE conv + add
  pe_kernel<<<1024, 256, 0, stream>>>(qkvb, oattn, pe_w, pe_b, tmp);
  // final projection
  conv1x1_kernel<256, false><<<512, 256, 0, stream>>>(tmp, proj_w, proj_b, out);
}

// Round 3
// 221.210 us; speedup vs baseline: 1.8096x; 1.5196x over previous
//
#include <hip/hip_runtime.h>
#include <math.h>

#define NTOK 1024
#define CAP 160

#define LDS_FENCE() asm volatile("s_waitcnt lgkmcnt(0)" ::: "memory")

typedef __bf16 bf16x8 __attribute__((ext_vector_type(8)));
typedef unsigned short u16x8 __attribute__((ext_vector_type(8)));
typedef unsigned short u16x4 __attribute__((ext_vector_type(4)));
typedef float f32x4 __attribute__((ext_vector_type(4)));

__device__ __forceinline__ unsigned short f2bf(float f) {
  unsigned int u = __float_as_uint(f);
  return (unsigned short)((u + 0x7fffu + ((u >> 16) & 1u)) >> 16);
}

// B=4, DIM=256, NH=8, HEAD_DIM=32, KEY_DIM=16, QKV_OUT=512, SCALE=0.25

// Generic conv1x1 / GEMM: out[b,oc,p] = bias[oc] + sum_c w[oc,c]*in[b,c,p]
// grid = B * (OC/8) * (NTOK/256), block = 256. 8 out-channels per thread.
// VCAST: also emit bf16 copy of the v-channels (oc%64 >= 32) for MFMA PV.
template<int OC, bool RELU, bool VCAST>
__global__ __launch_bounds__(256) void conv1x1_kernel(const float* __restrict__ in,
    const float* __restrict__ w, const float* __restrict__ bias, float* __restrict__ out,
    unsigned short* __restrict__ vbf) {
  __shared__ float wsm[256][8];
  int bid = blockIdx.x;
  const int pb = bid & 3; bid >>= 2;
  const int ocb = bid % (OC / 8); const int b = bid / (OC / 8);
  const int tid = threadIdx.x;
  for (int i = tid; i < 2048; i += 256) {
    int j = i >> 8, c = i & 255;
    wsm[c][j] = w[(size_t)(ocb * 8 + j) * 256 + c];
  }
  __syncthreads();
  const int p = pb * 256 + tid;
  const float* inb = in + (size_t)b * 256 * NTOK + p;
  float acc[8];
  #pragma unroll
  for (int j = 0; j < 8; j++) acc[j] = bias[ocb * 8 + j];
  #pragma unroll 4
  for (int c = 0; c < 256; c++) {
    float xv = inb[(size_t)c * NTOK];
    const float4 wa = *(const float4*)&wsm[c][0];
    const float4 wb = *(const float4*)&wsm[c][4];
    acc[0] = fmaf(wa.x, xv, acc[0]);
    acc[1] = fmaf(wa.y, xv, acc[1]);
    acc[2] = fmaf(wa.z, xv, acc[2]);
    acc[3] = fmaf(wa.w, xv, acc[3]);
    acc[4] = fmaf(wb.x, xv, acc[4]);
    acc[5] = fmaf(wb.y, xv, acc[5]);
    acc[6] = fmaf(wb.z, xv, acc[6]);
    acc[7] = fmaf(wb.w, xv, acc[7]);
  }
  #pragma unroll
  for (int j = 0; j < 8; j++) {
    float v = acc[j];
    if (RELU) v = fmaxf(v, 0.f);
    out[((size_t)b * OC + ocb * 8 + j) * NTOK + p] = v;
    if constexpr (VCAST) {
      const int oc = ocb * 8 + j;
      if ((oc & 63) >= 32) {
        const int c = (oc >> 6) * 32 + (oc & 63) - 32;
        vbf[((size_t)b * 256 + c) * NTOK + p] = f2bf(v);
      }
    }
  }
}

// g2 = sigmoid(g2_w . relu_g1 + g2_b), deterministic fp64 block partial sums
__global__ __launch_bounds__(256) void gate2_kernel(const float* __restrict__ gx,
    const float* __restrict__ g2_w, const float* __restrict__ g2_b, double* __restrict__ part) {
  const int idx = blockIdx.x * 256 + threadIdx.x;
  const int b = idx >> 10, p = idx & 1023;
  float acc = g2_b[0];
  const float* gb = gx + (size_t)b * 128 * NTOK + p;
  #pragma unroll 4
  for (int j = 0; j < 128; j++) acc = fmaf(g2_w[j], gb[(size_t)j * NTOK], acc);
  float g = 1.f / (1.f + expf(-acc));
  __shared__ double red[256];
  red[threadIdx.x] = (double)g;
  __syncthreads();
  for (int s = 128; s > 0; s >>= 1) {
    if (threadIdx.x < s) red[threadIdx.x] += red[threadIdx.x + s];
    __syncthreads();
  }
  if (threadIdx.x == 0) part[blockIdx.x] = red[0];
}

__global__ void dynk_kernel(const double* __restrict__ part, int* __restrict__ dynk) {
  double s = 0.0;
  for (int i = 0; i < 16; i++) s += part[i];
  double mean = s / 4096.0;
  int k = (int)floor(1024.0 * mean);
  if (k < 1) k = 1;
  if (k > NTOK) k = NTOK;
  *dynk = k;
}

// Attention: one block = 8 query rows of one (b,h). Wave-local exact top-dyn_k
// selection (2-level 64-bin value radix), fp32 logits (exact vs reference).
// PV via mfma_f32_16x16x32_bf16: P converted to bf16 in-place (aliases the
// wave-private logit row), V from precomputed bf16 buffer; k-split over waves.
__global__ __launch_bounds__(256) void attn_kernel(const float* __restrict__ qkv,
    const unsigned short* __restrict__ vbf,
    const int* __restrict__ dynk_p, float* __restrict__ out_attn) {
  const int tid = threadIdx.x;
  const int lane = tid & 63, wv = tid >> 6;
  int bid = blockIdx.x;
  const int mb = bid & 127; bid >>= 7;
  const int h = bid & 7; const int b = bid >> 3;
  int dk = *dynk_p;
  const int dyn_k = dk < 1 ? 1 : (dk > NTOK ? NTOK : dk);
  const float* base = qkv + (size_t)(b * 512 + h * 64) * NTOK;

  // Row storage: fp32 logits, later overwritten (wave-private) by bf16 P.
  __shared__ union RowU { float f[1028]; unsigned short pa[1032]; } rows[8];
  __shared__ float invs[8];
  __shared__ union UU {
    float qs[16][8];
    struct {
      int hist[4][64];
      int cnt[4];
      float Bv[4]; int Bn[4];
      struct { float v; int n; } cand[4][CAP];
    } sel;
    float pvred[4][8][33];
  } u;

  if (tid < 128)
    u.qs[tid >> 3][tid & 7] = base[(size_t)(tid >> 3) * NTOK + mb * 8 + (tid & 7)];
  __syncthreads();

  // ---- logits: thread computes n = 4*tid..4*tid+3 for all 8 rows ----
  {
    const float4* k4 = (const float4*)(base + 16 * NTOK);
    float acc[8][4];
    #pragma unroll
    for (int r = 0; r < 8; r++) { acc[r][0] = acc[r][1] = acc[r][2] = acc[r][3] = 0.f; }
    #pragma unroll
    for (int d = 0; d < 16; d++) {
      float4 kk = k4[d * 256 + tid];
      #pragma unroll
      for (int r = 0; r < 8; r++) {
        float qv = u.qs[d][r];
        acc[r][0] = fmaf(qv, kk.x, acc[r][0]);
        acc[r][1] = fmaf(qv, kk.y, acc[r][1]);
        acc[r][2] = fmaf(qv, kk.z, acc[r][2]);
        acc[r][3] = fmaf(qv, kk.w, acc[r][3]);
      }
    }
    #pragma unroll
    for (int r = 0; r < 8; r++)
      ((float4*)rows[r].f)[tid] = make_float4(acc[r][0] * 0.25f, acc[r][1] * 0.25f,
                                              acc[r][2] * 0.25f, acc[r][3] * 0.25f);
  }
  __syncthreads();   // logits ready; qs dead -> sel region live

  // ---- wave-local selection + softmax: wave wv owns rows 2*wv, 2*wv+1 ----
  for (int rr = 0; rr < 2; rr++) {
    const int r = wv * 2 + rr;
    float* smrow = rows[r].f;
    float v[16];
    {
      float4 f0 = ((const float4*)smrow)[lane];
      float4 f1 = ((const float4*)smrow)[64 + lane];
      float4 f2 = ((const float4*)smrow)[128 + lane];
      float4 f3 = ((const float4*)smrow)[192 + lane];
      v[0]=f0.x; v[1]=f0.y; v[2]=f0.z; v[3]=f0.w;
      v[4]=f1.x; v[5]=f1.y; v[6]=f1.z; v[7]=f1.w;
      v[8]=f2.x; v[9]=f2.y; v[10]=f2.z; v[11]=f2.w;
      v[12]=f3.x; v[13]=f3.y; v[14]=f3.z; v[15]=f3.w;
    }
    float mn = v[0], mx = v[0];
    #pragma unroll
    for (int i = 1; i < 16; i++) { mn = fminf(mn, v[i]); mx = fmaxf(mx, v[i]); }
    #pragma unroll
    for (int off = 32; off > 0; off >>= 1) {
      mn = fminf(mn, __shfl_xor(mn, off));
      mx = fmaxf(mx, __shfl_xor(mx, off));
    }

    unsigned int keepmask = 0xFFFFu;
    if (dyn_k < NTOK) {
      float Bv = mx; int Bn = dyn_k - 1;        // degenerate (all-equal) default
      const float range = mx - mn;
      const bool fine = (range > 0.f);
      int m = 0;
      if (fine) {
        const float s1 = 64.0f / range;
        // pass 1: 64 bins over [mn,mx]
        u.sel.hist[wv][lane] = 0;
        LDS_FENCE();
        int idx1[16];
        #pragma unroll
        for (int i = 0; i < 16; i++) {
          int ix = (int)((v[i] - mn) * s1);
          ix = ix < 0 ? 0 : (ix > 63 ? 63 : ix);
          idx1[i] = ix;
          atomicAdd(&u.sel.hist[wv][ix], 1);
        }
        LDS_FENCE();
        int cum = u.sel.hist[wv][lane];
        #pragma unroll
        for (int off = 1; off < 64; off <<= 1) {
          int o = __shfl_down(cum, off);
          if (lane + off < 64) cum += o;
        }
        int cumNext = __shfl_down(cum, 1);
        if (lane == 63) cumNext = 0;
        unsigned long long bal = __ballot(cum >= dyn_k && cumNext < dyn_k);
        const int t = (int)__builtin_ctzll(bal);
        const int k2 = dyn_k - __shfl(cumNext, t);
        // pass 2: 64 sub-bins within bin t
        const float binw = range * (1.0f / 64.0f);
        const float lo = mn + (float)t * binw;
        float s2 = 4096.0f / range;
        if (!(s2 < 3.0e38f)) s2 = 0.f;
        u.sel.hist[wv][lane] = 0;
        LDS_FENCE();
        #pragma unroll
        for (int i = 0; i < 16; i++) {
          if (idx1[i] == t) {
            int ix = (int)((v[i] - lo) * s2);
            ix = ix < 0 ? 0 : (ix > 63 ? 63 : ix);
            atomicAdd(&u.sel.hist[wv][ix], 1);
          }
        }
        LDS_FENCE();
        cum = u.sel.hist[wv][lane];
        #pragma unroll
        for (int off = 1; off < 64; off <<= 1) {
          int o = __shfl_down(cum, off);
          if (lane + off < 64) cum += o;
        }
        cumNext = __shfl_down(cum, 1);
        if (lane == 63) cumNext = 0;
        bal = __ballot(cum >= k2 && cumNext < k2);
        const int t2 = (int)__builtin_ctzll(bal);
        const int k3 = k2 - __shfl(cumNext, t2);
        // collect candidates in sub-bin (t,t2)
        if (lane == 0) u.sel.cnt[wv] = 0;
        LDS_FENCE();
        #pragma unroll
        for (int i = 0; i < 16; i++) {
          if (idx1[i] == t) {
            int ix = (int)((v[i] - lo) * s2);
            ix = ix < 0 ? 0 : (ix > 63 ? 63 : ix);
            if (ix == t2) {
              int p = atomicAdd(&u.sel.cnt[wv], 1);
              if (p < CAP) { u.sel.cand[wv][p].v = v[i]; u.sel.cand[wv][p].n = (i >> 2) * 256 + lane * 4 + (i & 3); }
            }
          }
        }
        LDS_FENCE();
        m = u.sel.cnt[wv];
        if (m <= CAP) {
          // exact boundary element: rank k3-1 among candidates (value desc, idx asc)
          for (int ii = lane; ii < m; ii += 64) {
            float cv = u.sel.cand[wv][ii].v; int cn = u.sel.cand[wv][ii].n;
            int rk = 0;
            for (int j = 0; j < m; j++) {
              float ov = u.sel.cand[wv][j].v; int on = u.sel.cand[wv][j].n;
              rk += ((ov > cv) || (ov == cv && on < cn)) ? 1 : 0;
            }
            if (rk == k3 - 1) { u.sel.Bv[wv] = cv; u.sel.Bn[wv] = cn; }
          }
          LDS_FENCE();
          Bv = u.sel.Bv[wv]; Bn = u.sel.Bn[wv];
        }
      }
      if (fine && m > CAP) {
        // exact fallback: brute-force rank vs whole row (never on smooth data)
        keepmask = 0u;
        #pragma unroll
        for (int i = 0; i < 16; i++) {
          const int n_i = (i >> 2) * 256 + lane * 4 + (i & 3);
          const float vi = v[i];
          int rk = 0;
          for (int j = 0; j < NTOK; j++) {
            float ov = smrow[j];
            rk += ((ov > vi) || (ov == vi && j < n_i)) ? 1 : 0;
          }
          if (rk < dyn_k) keepmask |= (1u << i);
        }
      } else {
        keepmask = 0u;
        #pragma unroll
        for (int i = 0; i < 16; i++) {
          const int n_i = (i >> 2) * 256 + lane * 4 + (i & 3);
          if ((v[i] > Bv) || (v[i] == Bv && n_i <= Bn)) keepmask |= (1u << i);
        }
      }
    }
    // softmax (row max mx is always kept: rank 0 < dyn_k)
    float e[16]; float s = 0.f;
    #pragma unroll
    for (int i = 0; i < 16; i++) {
      e[i] = ((keepmask >> i) & 1u) ? __expf(v[i] - mx) : 0.f;
      s += e[i];
    }
    #pragma unroll
    for (int off = 32; off > 0; off >>= 1) s += __shfl_xor(s, off);
    if (lane == 0) invs[r] = 1.f / s;
    // write bf16 P in-place (this wave owns row r; PV reads after barrier)
    #pragma unroll
    for (int j = 0; j < 4; j++) {
      u16x4 w4 = { f2bf(e[4*j]), f2bf(e[4*j+1]), f2bf(e[4*j+2]), f2bf(e[4*j+3]) };
      *(u16x4*)&rows[r].pa[j * 256 + lane * 4] = w4;
    }
  }
  __syncthreads();

  // ---- PV via MFMA: out[8x32] = P[8x1024] . V^T, k-split across 4 waves ----
  {
    const int g = lane >> 4;                 // k-group 0..3
    const int m16 = lane & 15;
    const unsigned short* vrow0 = vbf + ((size_t)(b * 256 + h * 32) + m16) * NTOK;
    const unsigned short* vrow1 = vrow0 + 16 * NTOK;
    const unsigned short* parow = rows[lane & 7].pa;   // rows 8..15 dup rows 0..7 (C rows 8..15 unused)
    f32x4 acc0 = {0.f, 0.f, 0.f, 0.f}, acc1 = {0.f, 0.f, 0.f, 0.f};
    const int n_base = wv * 256;
    #pragma unroll
    for (int ks = 0; ks < 8; ks++) {
      const int n0 = n_base + ks * 32 + g * 8;
      bf16x8 a  = __builtin_bit_cast(bf16x8, *(const u16x8*)&parow[n0]);
      bf16x8 b0 = __builtin_bit_cast(bf16x8, *(const u16x8*)&vrow0[n0]);
      bf16x8 b1 = __builtin_bit_cast(bf16x8, *(const u16x8*)&vrow1[n0]);
      acc0 = __builtin_amdgcn_mfma_f32_16x16x32_bf16(a, b0, acc0, 0, 0, 0);
      acc1 = __builtin_amdgcn_mfma_f32_16x16x32_bf16(a, b1, acc1, 0, 0, 0);
    }
    if (g < 2) {
      #pragma unroll
      for (int q = 0; q < 4; q++) {
        const int row = g * 4 + q;
        u.pvred[wv][row][m16]      = acc0[q];
        u.pvred[wv][row][16 + m16] = acc1[q];
      }
    }
  }
  __syncthreads();
  {
    const int r2 = tid & 7, d2 = tid >> 3;
    float s = u.pvred[0][r2][d2] + u.pvred[1][r2][d2]
            + u.pvred[2][r2][d2] + u.pvred[3][r2][d2];
    s *= invs[r2];
    out_attn[(size_t)(b * 256 + h * 32 + d2) * NTOK + mb * 8 + r2] = s;
  }
}

// depthwise 3x3 conv on v image + bias, fused add of attention output
__global__ __launch_bounds__(256) void pe_kernel(const float* __restrict__ qkv,
    const float* __restrict__ oattn, const float* __restrict__ pe_w,
    const float* __restrict__ pe_b, float* __restrict__ tmp) {
  int bid = blockIdx.x;
  const int c = bid & 255; const int b = bid >> 8;
  const int oc = ((c >> 5) * 64) + 32 + (c & 31);   // v channel within qkv layout
  const float* vimg = qkv + (size_t)(b * 512 + oc) * NTOK;
  float wloc[9];
  #pragma unroll
  for (int i = 0; i < 9; i++) wloc[i] = pe_w[c * 9 + i];
  const float bv = pe_b[c];
  const float* oa = oattn + (size_t)(b * 256 + c) * NTOK;
  float* tp = tmp + (size_t)(b * 256 + c) * NTOK;
  for (int p = threadIdx.x; p < NTOK; p += 256) {
    const int y = p >> 5, x = p & 31;
    float s = bv;
    #pragma unroll
    for (int dy = -1; dy <= 1; dy++) {
      int yy = y + dy;
      if (yy < 0 || yy > 31) continue;
      #pragma unroll
      for (int dx = -1; dx <= 1; dx++) {
        int xx = x + dx;
        if (xx < 0 || xx > 31) continue;
        s = fmaf(wloc[(dy + 1) * 3 + (dx + 1)], vimg[yy * 32 + xx], s);
      }
    }
    tp[p] = s + oa[p];
  }
}

extern "C" void kernel_launch(void* const* d_in, const int* in_sizes, int n_in,
                              void* d_out, int out_size, void* d_ws, size_t ws_size,
                              hipStream_t stream) {
  const float* x      = (const float*)d_in[0];
  const float* qkv_w  = (const float*)d_in[1];
  const float* qkv_b  = (const float*)d_in[2];
  const float* proj_w = (const float*)d_in[3];
  const float* proj_b = (const float*)d_in[4];
  const float* pe_w   = (const float*)d_in[5];
  const float* pe_b   = (const float*)d_in[6];
  const float* g1_w   = (const float*)d_in[7];
  const float* g1_b   = (const float*)d_in[8];
  const float* g2_w   = (const float*)d_in[9];
  const float* g2_b   = (const float*)d_in[10];
  float* out = (float*)d_out;

  char* ws = (char*)d_ws;
  float*  qkvb  = (float*)(ws);                          // B*512*1024*4 = 8 MB
  float*  oattn = (float*)(ws + (8u << 20));             // 4 MB
  float*  tmp   = (float*)(ws + (12u << 20));            // 4 MB (pe output)
  // vbf aliases tmp: written by qkv-conv, read by attn, dead before pe writes tmp
  unsigned short* vbf = (unsigned short*)(ws + (12u << 20));   // 2 MB bf16 V
  float*  gx    = (float*)(ws + (16u << 20));            // B*128*1024*4 = 2 MB
  double* part  = (double*)(ws + (18u << 20));           // 16 doubles
  int*    dynk  = (int*)(ws + (18u << 20) + 256);

  // gate path -> dyn_k (deterministic)
  conv1x1_kernel<128, true, false><<<256, 256, 0, stream>>>(x, g1_w, g1_b, gx, nullptr);
  gate2_kernel<<<16, 256, 0, stream>>>(gx, g2_w, g2_b, part);
  dynk_kernel<<<1, 1, 0, stream>>>(part, dynk);
  // qkv (+ fused bf16 cast of V channels)
  conv1x1_kernel<512, false, true><<<1024, 256, 0, stream>>>(x, qkv_w, qkv_b, qkvb, vbf);
  // attention with exact top-dyn_k masked softmax, MFMA PV
  attn_kernel<<<4096, 256, 0, stream>>>(qkvb, vbf, dynk, oattn);
  // depthwise PE conv + add (overwrites vbf region — attn already done)
  pe_kernel<<<1024, 256, 0, stream>>>(qkvb, oattn, pe_w, pe_b, tmp);
  // final projection
  conv1x1_kernel<256, false, false><<<512, 256, 0, stream>>>(tmp, proj_w, proj_b, out, nullptr);
}

// Round 4
// 197.987 us; speedup vs baseline: 2.0218x; 1.1173x over previous
//
#include <hip/hip_runtime.h>
#include <math.h>

#define NTOK 1024
#define CAP 64

#define LDS_FENCE() asm volatile("s_waitcnt lgkmcnt(0)" ::: "memory")

typedef __bf16 bf16x8 __attribute__((ext_vector_type(8)));
typedef unsigned short u16x8 __attribute__((ext_vector_type(8)));
typedef unsigned short u16x4 __attribute__((ext_vector_type(4)));
typedef float f32x4 __attribute__((ext_vector_type(4)));

__device__ __forceinline__ unsigned short f2bf(float f) {
  unsigned int u = __float_as_uint(f);
  return (unsigned short)((u + 0x7fffu + ((u >> 16) & 1u)) >> 16);
}

// B=4, DIM=256, NH=8, HEAD_DIM=32, KEY_DIM=16, QKV_OUT=512, SCALE=0.25

// conv1x1: out[b,oc,p] = bias[oc] + sum_c w[oc,c]*in[b,c,p]
// Weights are block-uniform -> uniform (scalar) loads, NO LDS.
// P positions per thread. grid = B * (OC/8) * (NTOK/(256*P)), block = 256.
template<int OC, int P, bool RELU, bool VCAST>
__global__ __launch_bounds__(256) void conv1x1_kernel(const float* __restrict__ in,
    const float* __restrict__ w, const float* __restrict__ bias, float* __restrict__ out,
    unsigned short* __restrict__ vbf) {
  constexpr int PB = NTOK / (256 * P);
  int bid = blockIdx.x;
  const int pb = bid % PB; bid /= PB;
  const int ocb = bid % (OC / 8); const int b = bid / (OC / 8);
  const int tid = threadIdx.x;
  const int p0 = pb * 256 * P + tid * P;
  const float* inb = in + (size_t)b * 256 * NTOK + p0;
  const float* wrow = w + (size_t)ocb * 8 * 256;

  float acc[8][P];
  #pragma unroll
  for (int j = 0; j < 8; j++)
    #pragma unroll
    for (int i = 0; i < P; i++) acc[j][i] = 0.f;

  #pragma unroll 2
  for (int c0 = 0; c0 < 256; c0 += 4) {
    float4 wl[8];
    #pragma unroll
    for (int j = 0; j < 8; j++) wl[j] = *(const float4*)&wrow[j * 256 + c0];  // uniform -> SGPR
    #pragma unroll
    for (int cc = 0; cc < 4; cc++) {
      float xr[P];
      if constexpr (P == 4) {
        float4 t = *(const float4*)&inb[(size_t)(c0 + cc) * NTOK];
        xr[0] = t.x; xr[1] = t.y; xr[2] = t.z; xr[3] = t.w;
      } else if constexpr (P == 2) {
        float2 t = *(const float2*)&inb[(size_t)(c0 + cc) * NTOK];
        xr[0] = t.x; xr[1] = t.y;
      } else {
        xr[0] = inb[(size_t)(c0 + cc) * NTOK];
      }
      #pragma unroll
      for (int j = 0; j < 8; j++) {
        const float wjc = ((const float*)&wl[j])[cc];
        #pragma unroll
        for (int i = 0; i < P; i++) acc[j][i] = fmaf(wjc, xr[i], acc[j][i]);
      }
    }
  }
  #pragma unroll
  for (int j = 0; j < 8; j++) {
    const int oc = ocb * 8 + j;
    const float bv = bias[oc];
    float r[P];
    #pragma unroll
    for (int i = 0; i < P; i++) {
      float v = acc[j][i] + bv;
      if (RELU) v = fmaxf(v, 0.f);
      r[i] = v;
    }
    float* op = out + ((size_t)b * OC + oc) * NTOK + p0;
    if constexpr (P == 4) *(float4*)op = make_float4(r[0], r[1], r[2], r[3]);
    else if constexpr (P == 2) *(float2*)op = make_float2(r[0], r[1]);
    else *op = r[0];
    if constexpr (VCAST) {
      if ((oc & 63) >= 32) {
        const int c = (oc >> 6) * 32 + (oc & 63) - 32;
        unsigned short* vp = vbf + ((size_t)b * 256 + c) * NTOK + p0;
        if constexpr (P == 4) {
          u16x4 w4 = { f2bf(r[0]), f2bf(r[1]), f2bf(r[2]), f2bf(r[3]) };
          *(u16x4*)vp = w4;
        } else {
          #pragma unroll
          for (int i = 0; i < P; i++) vp[i] = f2bf(r[i]);
        }
      }
    }
  }
}

// g2 = sigmoid(g2_w . relu_g1 + g2_b), deterministic fp64 block partial sums
__global__ __launch_bounds__(256) void gate2_kernel(const float* __restrict__ gx,
    const float* __restrict__ g2_w, const float* __restrict__ g2_b, double* __restrict__ part) {
  const int idx = blockIdx.x * 256 + threadIdx.x;
  const int b = idx >> 10, p = idx & 1023;
  float acc = g2_b[0];
  const float* gb = gx + (size_t)b * 128 * NTOK + p;
  #pragma unroll 4
  for (int j = 0; j < 128; j++) acc = fmaf(g2_w[j], gb[(size_t)j * NTOK], acc);
  float g = 1.f / (1.f + expf(-acc));
  __shared__ double red[256];
  red[threadIdx.x] = (double)g;
  __syncthreads();
  for (int s = 128; s > 0; s >>= 1) {
    if (threadIdx.x < s) red[threadIdx.x] += red[threadIdx.x + s];
    __syncthreads();
  }
  if (threadIdx.x == 0) part[blockIdx.x] = red[0];
}

// Attention: one block = 8 query rows of one (b,h), 512 threads, 1 row PER WAVE.
// dyn_k computed inline from gate partials (identical serial fp64 order).
// Exact top-dyn_k: 2-level 64-bin value radix -> boundary (value,index) ->
// keep = (v > Bv) || (v == Bv && n <= Bn)   [stable-argsort tie rule].
// PV via mfma_f32_16x16x32_bf16, 4 k-slices x 2 d-tiles across 8 waves.
__global__ __launch_bounds__(512) void attn_kernel(const float* __restrict__ qkv,
    const unsigned short* __restrict__ vbf,
    const double* __restrict__ part, float* __restrict__ out_attn) {
  const int tid = threadIdx.x;
  const int lane = tid & 63, wv = tid >> 6;
  int bid = blockIdx.x;
  const int mb = bid & 127; bid >>= 7;
  const int h = bid & 7; const int b = bid >> 3;

  double dsum = 0.0;
  #pragma unroll
  for (int i = 0; i < 16; i++) dsum += part[i];
  int dk = (int)floor(1024.0 * (dsum / 4096.0));
  const int dyn_k = dk < 1 ? 1 : (dk > NTOK ? NTOK : dk);

  const float* base = qkv + (size_t)(b * 512 + h * 64) * NTOK;

  __shared__ union RowU { float f[1028]; unsigned short pa[1032]; } rows[8];
  __shared__ float invs[8];
  __shared__ union UU {
    float qs[16][8];
    struct {
      int hist[8][64];
      int cnt[8];
      float Bv[8]; int Bn[8];
      struct { float v; int n; } cand[8][CAP];
    } sel;
    float pvred[2][4][8][17];
  } u;

  if (tid < 128)
    u.qs[tid >> 3][tid & 7] = base[(size_t)(tid >> 3) * NTOK + mb * 8 + (tid & 7)];
  __syncthreads();

  // ---- logits: thread computes n = 2*tid, 2*tid+1 for all 8 rows ----
  {
    const float2* k2 = (const float2*)(base + 16 * NTOK);
    float a0[8], a1[8];
    #pragma unroll
    for (int r = 0; r < 8; r++) { a0[r] = 0.f; a1[r] = 0.f; }
    #pragma unroll
    for (int d = 0; d < 16; d++) {
      float2 kk = k2[d * 512 + tid];
      #pragma unroll
      for (int r = 0; r < 8; r++) {
        float qv = u.qs[d][r];
        a0[r] = fmaf(qv, kk.x, a0[r]);
        a1[r] = fmaf(qv, kk.y, a1[r]);
      }
    }
    #pragma unroll
    for (int r = 0; r < 8; r++)
      ((float2*)rows[r].f)[tid] = make_float2(a0[r] * 0.25f, a1[r] * 0.25f);
  }
  __syncthreads();   // logits ready; qs dead -> sel region live

  // ---- wave-local selection + softmax: wave wv owns row wv ----
  {
    const int r = wv;
    float* smrow = rows[r].f;
    float v[16];
    {
      float4 f0 = ((const float4*)smrow)[lane];
      float4 f1 = ((const float4*)smrow)[64 + lane];
      float4 f2 = ((const float4*)smrow)[128 + lane];
      float4 f3 = ((const float4*)smrow)[192 + lane];
      v[0]=f0.x; v[1]=f0.y; v[2]=f0.z; v[3]=f0.w;
      v[4]=f1.x; v[5]=f1.y; v[6]=f1.z; v[7]=f1.w;
      v[8]=f2.x; v[9]=f2.y; v[10]=f2.z; v[11]=f2.w;
      v[12]=f3.x; v[13]=f3.y; v[14]=f3.z; v[15]=f3.w;
    }
    float mn = v[0], mx = v[0];
    #pragma unroll
    for (int i = 1; i < 16; i++) { mn = fminf(mn, v[i]); mx = fmaxf(mx, v[i]); }
    #pragma unroll
    for (int off = 32; off > 0; off >>= 1) {
      mn = fminf(mn, __shfl_xor(mn, off));
      mx = fmaxf(mx, __shfl_xor(mx, off));
    }

    unsigned int keepmask = 0xFFFFu;
    if (dyn_k < NTOK) {
      float Bv = mx; int Bn = dyn_k - 1;        // degenerate (all-equal) default
      const float range = mx - mn;
      const bool fine = (range > 0.f);
      int m = 0;
      if (fine) {
        const float s1 = 64.0f / range;
        // pass 1: 64 bins over [mn,mx]
        u.sel.hist[wv][lane] = 0;
        LDS_FENCE();
        int idx1[16];
        #pragma unroll
        for (int i = 0; i < 16; i++) {
          int ix = (int)((v[i] - mn) * s1);
          ix = ix < 0 ? 0 : (ix > 63 ? 63 : ix);
          idx1[i] = ix;
          atomicAdd(&u.sel.hist[wv][ix], 1);
        }
        LDS_FENCE();
        int cum = u.sel.hist[wv][lane];
        #pragma unroll
        for (int off = 1; off < 64; off <<= 1) {
          int o = __shfl_down(cum, off);
          if (lane + off < 64) cum += o;
        }
        int cumNext = __shfl_down(cum, 1);
        if (lane == 63) cumNext = 0;
        unsigned long long bal = __ballot(cum >= dyn_k && cumNext < dyn_k);
        const int t = (int)__builtin_ctzll(bal);
        const int k2 = dyn_k - __shfl(cumNext, t);
        // pass 2: 64 sub-bins within bin t
        const float binw = range * (1.0f / 64.0f);
        const float lo = mn + (float)t * binw;
        float s2 = 4096.0f / range;
        if (!(s2 < 3.0e38f)) s2 = 0.f;
        u.sel.hist[wv][lane] = 0;
        LDS_FENCE();
        #pragma unroll
        for (int i = 0; i < 16; i++) {
          if (idx1[i] == t) {
            int ix = (int)((v[i] - lo) * s2);
            ix = ix < 0 ? 0 : (ix > 63 ? 63 : ix);
            atomicAdd(&u.sel.hist[wv][ix], 1);
          }
        }
        LDS_FENCE();
        cum = u.sel.hist[wv][lane];
        #pragma unroll
        for (int off = 1; off < 64; off <<= 1) {
          int o = __shfl_down(cum, off);
          if (lane + off < 64) cum += o;
        }
        cumNext = __shfl_down(cum, 1);
        if (lane == 63) cumNext = 0;
        bal = __ballot(cum >= k2 && cumNext < k2);
        const int t2 = (int)__builtin_ctzll(bal);
        const int k3 = k2 - __shfl(cumNext, t2);
        // collect candidates in sub-bin (t,t2)
        if (lane == 0) u.sel.cnt[wv] = 0;
        LDS_FENCE();
        #pragma unroll
        for (int i = 0; i < 16; i++) {
          if (idx1[i] == t) {
            int ix = (int)((v[i] - lo) * s2);
            ix = ix < 0 ? 0 : (ix > 63 ? 63 : ix);
            if (ix == t2) {
              int p = atomicAdd(&u.sel.cnt[wv], 1);
              if (p < CAP) { u.sel.cand[wv][p].v = v[i]; u.sel.cand[wv][p].n = (i >> 2) * 256 + lane * 4 + (i & 3); }
            }
          }
        }
        LDS_FENCE();
        m = u.sel.cnt[wv];
        if (m <= CAP) {
          // exact boundary element: rank k3-1 among candidates (value desc, idx asc)
          for (int ii = lane; ii < m; ii += 64) {
            float cv = u.sel.cand[wv][ii].v; int cn = u.sel.cand[wv][ii].n;
            int rk = 0;
            for (int j = 0; j < m; j++) {
              float ov = u.sel.cand[wv][j].v; int on = u.sel.cand[wv][j].n;
              rk += ((ov > cv) || (ov == cv && on < cn)) ? 1 : 0;
            }
            if (rk == k3 - 1) { u.sel.Bv[wv] = cv; u.sel.Bn[wv] = cn; }
          }
          LDS_FENCE();
          Bv = u.sel.Bv[wv]; Bn = u.sel.Bn[wv];
        }
      }
      if (fine && m > CAP) {
        // exact fallback: brute-force rank vs whole row (never on smooth data)
        keepmask = 0u;
        #pragma unroll
        for (int i = 0; i < 16; i++) {
          const int n_i = (i >> 2) * 256 + lane * 4 + (i & 3);
          const float vi = v[i];
          int rk = 0;
          for (int j = 0; j < NTOK; j++) {
            float ov = smrow[j];
            rk += ((ov > vi) || (ov == vi && j < n_i)) ? 1 : 0;
          }
          if (rk < dyn_k) keepmask |= (1u << i);
        }
      } else {
        keepmask = 0u;
        #pragma unroll
        for (int i = 0; i < 16; i++) {
          const int n_i = (i >> 2) * 256 + lane * 4 + (i & 3);
          if ((v[i] > Bv) || (v[i] == Bv && n_i <= Bn)) keepmask |= (1u << i);
        }
      }
    }
    // softmax (row max mx is always kept: rank 0 < dyn_k)
    float e[16]; float s = 0.f;
    #pragma unroll
    for (int i = 0; i < 16; i++) {
      e[i] = ((keepmask >> i) & 1u) ? __expf(v[i] - mx) : 0.f;
      s += e[i];
    }
    #pragma unroll
    for (int off = 32; off > 0; off >>= 1) s += __shfl_xor(s, off);
    if (lane == 0) invs[r] = 1.f / s;
    // write bf16 P in-place (this wave owns row r; PV reads after barrier)
    #pragma unroll
    for (int j = 0; j < 4; j++) {
      u16x4 w4 = { f2bf(e[4*j]), f2bf(e[4*j+1]), f2bf(e[4*j+2]), f2bf(e[4*j+3]) };
      *(u16x4*)&rows[r].pa[j * 256 + lane * 4] = w4;
    }
  }
  __syncthreads();

  // ---- PV via MFMA: out[8x32] = P[8x1024].V^T; 4 k-slices x 2 d-tiles ----
  {
    const int g = lane >> 4;                 // k-group 0..3
    const int m16 = lane & 15;
    const int ksl = wv & 3, dt = wv >> 2;
    const unsigned short* vrow = vbf + ((size_t)(b * 256 + h * 32 + dt * 16 + m16)) * NTOK;
    const unsigned short* parow = rows[lane & 7].pa;   // A rows 8..15 dup rows 0..7 (C rows 8..15 unused)
    f32x4 acc = {0.f, 0.f, 0.f, 0.f};
    const int nb = ksl * 256;
    #pragma unroll
    for (int ks = 0; ks < 8; ks++) {
      const int n0 = nb + ks * 32 + g * 8;
      bf16x8 a  = __builtin_bit_cast(bf16x8, *(const u16x8*)&parow[n0]);
      bf16x8 b0 = __builtin_bit_cast(bf16x8, *(const u16x8*)&vrow[n0]);
      acc = __builtin_amdgcn_mfma_f32_16x16x32_bf16(a, b0, acc, 0, 0, 0);
    }
    if (g < 2) {
      #pragma unroll
      for (int q = 0; q < 4; q++)
        u.pvred[dt][ksl][g * 4 + q][m16] = acc[q];
    }
  }
  __syncthreads();
  if (tid < 256) {
    const int r2 = tid & 7, d2 = tid >> 3;
    const int dt = d2 >> 4, m16 = d2 & 15;
    float s = u.pvred[dt][0][r2][m16] + u.pvred[dt][1][r2][m16]
            + u.pvred[dt][2][r2][m16] + u.pvred[dt][3][r2][m16];
    s *= invs[r2];
    out_attn[(size_t)(b * 256 + h * 32 + d2) * NTOK + mb * 8 + r2] = s;
  }
}

// depthwise 3x3 conv on v image + bias, fused add of attention output
__global__ __launch_bounds__(256) void pe_kernel(const float* __restrict__ qkv,
    const float* __restrict__ oattn, const float* __restrict__ pe_w,
    const float* __restrict__ pe_b, float* __restrict__ tmp) {
  int bid = blockIdx.x;
  const int c = bid & 255; const int b = bid >> 8;
  const int oc = ((c >> 5) * 64) + 32 + (c & 31);   // v channel within qkv layout
  const float* vimg = qkv + (size_t)(b * 512 + oc) * NTOK;
  float wloc[9];
  #pragma unroll
  for (int i = 0; i < 9; i++) wloc[i] = pe_w[c * 9 + i];
  const float bv = pe_b[c];
  const float* oa = oattn + (size_t)(b * 256 + c) * NTOK;
  float* tp = tmp + (size_t)(b * 256 + c) * NTOK;
  for (int p = threadIdx.x; p < NTOK; p += 256) {
    const int y = p >> 5, x = p & 31;
    float s = bv;
    #pragma unroll
    for (int dy = -1; dy <= 1; dy++) {
      int yy = y + dy;
      if (yy < 0 || yy > 31) continue;
      #pragma unroll
      for (int dx = -1; dx <= 1; dx++) {
        int xx = x + dx;
        if (xx < 0 || xx > 31) continue;
        s = fmaf(wloc[(dy + 1) * 3 + (dx + 1)], vimg[yy * 32 + xx], s);
      }
    }
    tp[p] = s + oa[p];
  }
}

extern "C" void kernel_launch(void* const* d_in, const int* in_sizes, int n_in,
                              void* d_out, int out_size, void* d_ws, size_t ws_size,
                              hipStream_t stream) {
  const float* x      = (const float*)d_in[0];
  const float* qkv_w  = (const float*)d_in[1];
  const float* qkv_b  = (const float*)d_in[2];
  const float* proj_w = (const float*)d_in[3];
  const float* proj_b = (const float*)d_in[4];
  const float* pe_w   = (const float*)d_in[5];
  const float* pe_b   = (const float*)d_in[6];
  const float* g1_w   = (const float*)d_in[7];
  const float* g1_b   = (const float*)d_in[8];
  const float* g2_w   = (const float*)d_in[9];
  const float* g2_b   = (const float*)d_in[10];
  float* out = (float*)d_out;

  char* ws = (char*)d_ws;
  float*  qkvb  = (float*)(ws);                          // B*512*1024*4 = 8 MB
  float*  oattn = (float*)(ws + (8u << 20));             // 4 MB
  float*  tmp   = (float*)(ws + (12u << 20));            // 4 MB (pe output)
  // vbf aliases tmp: written by qkv-conv, read by attn, dead before pe writes tmp
  unsigned short* vbf = (unsigned short*)(ws + (12u << 20));   // 2 MB bf16 V
  float*  gx    = (float*)(ws + (16u << 20));            // B*128*1024*4 = 2 MB
  double* part  = (double*)(ws + (18u << 20));           // 16 doubles

  // gate path -> partials (dyn_k computed inside attn)
  conv1x1_kernel<128, 1, true, false><<<256, 256, 0, stream>>>(x, g1_w, g1_b, gx, nullptr);
  gate2_kernel<<<16, 256, 0, stream>>>(gx, g2_w, g2_b, part);
  // qkv (+ fused bf16 cast of V channels)
  conv1x1_kernel<512, 4, false, true><<<256, 256, 0, stream>>>(x, qkv_w, qkv_b, qkvb, vbf);
  // attention with exact top-dyn_k masked softmax, MFMA PV
  attn_kernel<<<4096, 512, 0, stream>>>(qkvb, vbf, part, oattn);
  // depthwise PE conv + add (overwrites vbf region — attn already done)
  pe_kernel<<<1024, 256, 0, stream>>>(qkvb, oattn, pe_w, pe_b, tmp);
  // final projection
  conv1x1_kernel<256, 2, false, false><<<256, 256, 0, stream>>>(tmp, proj_w, proj_b, out, nullptr);
}

// Round 5
// 194.499 us; speedup vs baseline: 2.0581x; 1.0179x over previous
//
#include <hip/hip_runtime.h>
#include <math.h>

#define NTOK 1024
#define CAP 64

#define LDS_FENCE() asm volatile("s_waitcnt lgkmcnt(0)" ::: "memory")

typedef __bf16 bf16x8 __attribute__((ext_vector_type(8)));
typedef unsigned short u16x8 __attribute__((ext_vector_type(8)));
typedef unsigned short u16x4 __attribute__((ext_vector_type(4)));
typedef float f32x4 __attribute__((ext_vector_type(4)));

__device__ __forceinline__ unsigned short f2bf(float f) {
  unsigned int u = __float_as_uint(f);
  return (unsigned short)((u + 0x7fffu + ((u >> 16) & 1u)) >> 16);
}

// B=4, DIM=256, NH=8, HEAD_DIM=32, KEY_DIM=16, QKV_OUT=512, SCALE=0.25

// conv1x1: out[b,oc,p] = bias[oc] + sum_c w[oc,c]*in[b,c,p]
// Block-uniform weights -> scalar loads, no LDS. OCB out-channels and P
// positions per thread. grid = B * (OC/OCB) * (NTOK/(256*P)), block = 256.
template<int OC, int OCB, int P, bool RELU, bool VCAST>
__global__ __launch_bounds__(256) void conv1x1_kernel(const float* __restrict__ in,
    const float* __restrict__ w, const float* __restrict__ bias, float* __restrict__ out,
    unsigned short* __restrict__ vbf) {
  constexpr int PB = NTOK / (256 * P);
  int bid = blockIdx.x;
  const int pb = bid % PB; bid /= PB;
  const int ocb = bid % (OC / OCB); const int b = bid / (OC / OCB);
  const int tid = threadIdx.x;
  const int p0 = pb * 256 * P + tid * P;
  const float* inb = in + (size_t)b * 256 * NTOK + p0;
  const float* wrow = w + (size_t)ocb * OCB * 256;

  float acc[OCB][P];
  #pragma unroll
  for (int j = 0; j < OCB; j++)
    #pragma unroll
    for (int i = 0; i < P; i++) acc[j][i] = 0.f;

  #pragma unroll 2
  for (int c0 = 0; c0 < 256; c0 += 4) {
    float4 wl[OCB];
    #pragma unroll
    for (int j = 0; j < OCB; j++) wl[j] = *(const float4*)&wrow[j * 256 + c0];  // uniform -> SGPR
    #pragma unroll
    for (int cc = 0; cc < 4; cc++) {
      float xr[P];
      if constexpr (P == 4) {
        float4 t = *(const float4*)&inb[(size_t)(c0 + cc) * NTOK];
        xr[0] = t.x; xr[1] = t.y; xr[2] = t.z; xr[3] = t.w;
      } else if constexpr (P == 2) {
        float2 t = *(const float2*)&inb[(size_t)(c0 + cc) * NTOK];
        xr[0] = t.x; xr[1] = t.y;
      } else {
        xr[0] = inb[(size_t)(c0 + cc) * NTOK];
      }
      #pragma unroll
      for (int j = 0; j < OCB; j++) {
        const float wjc = ((const float*)&wl[j])[cc];
        #pragma unroll
        for (int i = 0; i < P; i++) acc[j][i] = fmaf(wjc, xr[i], acc[j][i]);
      }
    }
  }
  #pragma unroll
  for (int j = 0; j < OCB; j++) {
    const int oc = ocb * OCB + j;
    const float bv = bias[oc];
    float r[P];
    #pragma unroll
    for (int i = 0; i < P; i++) {
      float v = acc[j][i] + bv;
      if (RELU) v = fmaxf(v, 0.f);
      r[i] = v;
    }
    float* op = out + ((size_t)b * OC + oc) * NTOK + p0;
    if constexpr (P == 4) *(float4*)op = make_float4(r[0], r[1], r[2], r[3]);
    else if constexpr (P == 2) *(float2*)op = make_float2(r[0], r[1]);
    else *op = r[0];
    if constexpr (VCAST) {
      if ((oc & 63) >= 32) {
        const int c = (oc >> 6) * 32 + (oc & 63) - 32;
        unsigned short* vp = vbf + ((size_t)b * 256 + c) * NTOK + p0;
        #pragma unroll
        for (int i = 0; i < P; i++) vp[i] = f2bf(r[i]);
      }
    }
  }
}

// g2 = sigmoid(g2_w . relu_g1 + g2_b), deterministic fp64 block partial sums
__global__ __launch_bounds__(256) void gate2_kernel(const float* __restrict__ gx,
    const float* __restrict__ g2_w, const float* __restrict__ g2_b, double* __restrict__ part) {
  const int idx = blockIdx.x * 256 + threadIdx.x;
  const int b = idx >> 10, p = idx & 1023;
  float acc = g2_b[0];
  const float* gb = gx + (size_t)b * 128 * NTOK + p;
  #pragma unroll 4
  for (int j = 0; j < 128; j++) acc = fmaf(g2_w[j], gb[(size_t)j * NTOK], acc);
  float g = 1.f / (1.f + expf(-acc));
  __shared__ double red[256];
  red[threadIdx.x] = (double)g;
  __syncthreads();
  for (int s = 128; s > 0; s >>= 1) {
    if (threadIdx.x < s) red[threadIdx.x] += red[threadIdx.x + s];
    __syncthreads();
  }
  if (threadIdx.x == 0) part[blockIdx.x] = red[0];
}

// Attention: one block = 8 query rows of one (b,h), 512 threads, 1 row PER WAVE.
// dyn_k inline from gate partials. Exact top-dyn_k (2-level 64-bin value radix
// -> boundary (value,index); keep = v>Bv || (v==Bv && n<=Bn)). PV via
// mfma_f32_16x16x32_bf16. Epilogue fuses the depthwise 3x3 PE conv (fp32)
// and writes tmp = attn + pe directly.
__global__ __launch_bounds__(512) void attn_kernel(const float* __restrict__ qkv,
    const unsigned short* __restrict__ vbf, const double* __restrict__ part,
    const float* __restrict__ pe_w, const float* __restrict__ pe_b,
    float* __restrict__ tmp) {
  const int tid = threadIdx.x;
  const int lane = tid & 63, wv = tid >> 6;
  int bid = blockIdx.x;
  const int mb = bid & 127; bid >>= 7;
  const int h = bid & 7; const int b = bid >> 3;

  double dsum = 0.0;
  #pragma unroll
  for (int i = 0; i < 16; i++) dsum += part[i];
  int dk = (int)floor(1024.0 * (dsum / 4096.0));
  const int dyn_k = dk < 1 ? 1 : (dk > NTOK ? NTOK : dk);

  const float* base = qkv + (size_t)(b * 512 + h * 64) * NTOK;

  __shared__ union RowU { float f[1028]; unsigned short pa[1032]; } rows[8];
  __shared__ float invs[8];
  __shared__ union UU {
    float qs[16][8];
    struct {
      int hist[8][64];
      int cnt[8];
      float Bv[8]; int Bn[8];
      struct { float v; int n; } cand[8][CAP];
    } sel;
    float pvred[2][4][8][17];
  } u;

  if (tid < 128)
    u.qs[tid >> 3][tid & 7] = base[(size_t)(tid >> 3) * NTOK + mb * 8 + (tid & 7)];
  __syncthreads();

  // ---- logits: thread computes n = 2*tid, 2*tid+1 for all 8 rows ----
  {
    const float2* k2 = (const float2*)(base + 16 * NTOK);
    float a0[8], a1[8];
    #pragma unroll
    for (int r = 0; r < 8; r++) { a0[r] = 0.f; a1[r] = 0.f; }
    #pragma unroll
    for (int d = 0; d < 16; d++) {
      float2 kk = k2[d * 512 + tid];
      #pragma unroll
      for (int r = 0; r < 8; r++) {
        float qv = u.qs[d][r];
        a0[r] = fmaf(qv, kk.x, a0[r]);
        a1[r] = fmaf(qv, kk.y, a1[r]);
      }
    }
    #pragma unroll
    for (int r = 0; r < 8; r++)
      ((float2*)rows[r].f)[tid] = make_float2(a0[r] * 0.25f, a1[r] * 0.25f);
  }
  __syncthreads();   // logits ready; qs dead -> sel region live

  // ---- wave-local selection + softmax: wave wv owns row wv ----
  {
    const int r = wv;
    float* smrow = rows[r].f;
    float v[16];
    {
      float4 f0 = ((const float4*)smrow)[lane];
      float4 f1 = ((const float4*)smrow)[64 + lane];
      float4 f2 = ((const float4*)smrow)[128 + lane];
      float4 f3 = ((const float4*)smrow)[192 + lane];
      v[0]=f0.x; v[1]=f0.y; v[2]=f0.z; v[3]=f0.w;
      v[4]=f1.x; v[5]=f1.y; v[6]=f1.z; v[7]=f1.w;
      v[8]=f2.x; v[9]=f2.y; v[10]=f2.z; v[11]=f2.w;
      v[12]=f3.x; v[13]=f3.y; v[14]=f3.z; v[15]=f3.w;
    }
    float mn = v[0], mx = v[0];
    #pragma unroll
    for (int i = 1; i < 16; i++) { mn = fminf(mn, v[i]); mx = fmaxf(mx, v[i]); }
    #pragma unroll
    for (int off = 32; off > 0; off >>= 1) {
      mn = fminf(mn, __shfl_xor(mn, off));
      mx = fmaxf(mx, __shfl_xor(mx, off));
    }

    unsigned int keepmask = 0xFFFFu;
    if (dyn_k < NTOK) {
      float Bv = mx; int Bn = dyn_k - 1;        // degenerate (all-equal) default
      const float range = mx - mn;
      const bool fine = (range > 0.f);
      int m = 0;
      if (fine) {
        const float s1 = 64.0f / range;
        // pass 1: 64 bins over [mn,mx]
        u.sel.hist[wv][lane] = 0;
        LDS_FENCE();
        int idx1[16];
        #pragma unroll
        for (int i = 0; i < 16; i++) {
          int ix = (int)((v[i] - mn) * s1);
          ix = ix < 0 ? 0 : (ix > 63 ? 63 : ix);
          idx1[i] = ix;
          atomicAdd(&u.sel.hist[wv][ix], 1);
        }
        LDS_FENCE();
        int cum = u.sel.hist[wv][lane];
        #pragma unroll
        for (int off = 1; off < 64; off <<= 1) {
          int o = __shfl_down(cum, off);
          if (lane + off < 64) cum += o;
        }
        int cumNext = __shfl_down(cum, 1);
        if (lane == 63) cumNext = 0;
        unsigned long long bal = __ballot(cum >= dyn_k && cumNext < dyn_k);
        const int t = (int)__builtin_ctzll(bal);
        const int k2 = dyn_k - __shfl(cumNext, t);
        // pass 2: 64 sub-bins within bin t
        const float binw = range * (1.0f / 64.0f);
        const float lo = mn + (float)t * binw;
        float s2 = 4096.0f / range;
        if (!(s2 < 3.0e38f)) s2 = 0.f;
        u.sel.hist[wv][lane] = 0;
        LDS_FENCE();
        #pragma unroll
        for (int i = 0; i < 16; i++) {
          if (idx1[i] == t) {
            int ix = (int)((v[i] - lo) * s2);
            ix = ix < 0 ? 0 : (ix > 63 ? 63 : ix);
            atomicAdd(&u.sel.hist[wv][ix], 1);
          }
        }
        LDS_FENCE();
        cum = u.sel.hist[wv][lane];
        #pragma unroll
        for (int off = 1; off < 64; off <<= 1) {
          int o = __shfl_down(cum, off);
          if (lane + off < 64) cum += o;
        }
        cumNext = __shfl_down(cum, 1);
        if (lane == 63) cumNext = 0;
        bal = __ballot(cum >= k2 && cumNext < k2);
        const int t2 = (int)__builtin_ctzll(bal);
        const int k3 = k2 - __shfl(cumNext, t2);
        // collect candidates in sub-bin (t,t2)
        if (lane == 0) u.sel.cnt[wv] = 0;
        LDS_FENCE();
        #pragma unroll
        for (int i = 0; i < 16; i++) {
          if (idx1[i] == t) {
            int ix = (int)((v[i] - lo) * s2);
            ix = ix < 0 ? 0 : (ix > 63 ? 63 : ix);
            if (ix == t2) {
              int p = atomicAdd(&u.sel.cnt[wv], 1);
              if (p < CAP) { u.sel.cand[wv][p].v = v[i]; u.sel.cand[wv][p].n = (i >> 2) * 256 + lane * 4 + (i & 3); }
            }
          }
        }
        LDS_FENCE();
        m = u.sel.cnt[wv];
        if (m <= CAP) {
          // exact boundary element: rank k3-1 among candidates (value desc, idx asc)
          for (int ii = lane; ii < m; ii += 64) {
            float cv = u.sel.cand[wv][ii].v; int cn = u.sel.cand[wv][ii].n;
            int rk = 0;
            for (int j = 0; j < m; j++) {
              float ov = u.sel.cand[wv][j].v; int on = u.sel.cand[wv][j].n;
              rk += ((ov > cv) || (ov == cv && on < cn)) ? 1 : 0;
            }
            if (rk == k3 - 1) { u.sel.Bv[wv] = cv; u.sel.Bn[wv] = cn; }
          }
          LDS_FENCE();
          Bv = u.sel.Bv[wv]; Bn = u.sel.Bn[wv];
        }
      }
      if (fine && m > CAP) {
        // exact fallback: brute-force rank vs whole row (never on smooth data)
        keepmask = 0u;
        #pragma unroll
        for (int i = 0; i < 16; i++) {
          const int n_i = (i >> 2) * 256 + lane * 4 + (i & 3);
          const float vi = v[i];
          int rk = 0;
          for (int j = 0; j < NTOK; j++) {
            float ov = smrow[j];
            rk += ((ov > vi) || (ov == vi && j < n_i)) ? 1 : 0;
          }
          if (rk < dyn_k) keepmask |= (1u << i);
        }
      } else {
        keepmask = 0u;
        #pragma unroll
        for (int i = 0; i < 16; i++) {
          const int n_i = (i >> 2) * 256 + lane * 4 + (i & 3);
          if ((v[i] > Bv) || (v[i] == Bv && n_i <= Bn)) keepmask |= (1u << i);
        }
      }
    }
    // softmax (row max mx is always kept: rank 0 < dyn_k)
    float e[16]; float s = 0.f;
    #pragma unroll
    for (int i = 0; i < 16; i++) {
      e[i] = ((keepmask >> i) & 1u) ? __expf(v[i] - mx) : 0.f;
      s += e[i];
    }
    #pragma unroll
    for (int off = 32; off > 0; off >>= 1) s += __shfl_xor(s, off);
    if (lane == 0) invs[r] = 1.f / s;
    // write bf16 P in-place (this wave owns row r; PV reads after barrier)
    #pragma unroll
    for (int j = 0; j < 4; j++) {
      u16x4 w4 = { f2bf(e[4*j]), f2bf(e[4*j+1]), f2bf(e[4*j+2]), f2bf(e[4*j+3]) };
      *(u16x4*)&rows[r].pa[j * 256 + lane * 4] = w4;
    }
  }
  __syncthreads();

  // ---- PV via MFMA: out[8x32] = P[8x1024].V^T; 4 k-slices x 2 d-tiles ----
  {
    const int g = lane >> 4;                 // k-group 0..3
    const int m16 = lane & 15;
    const int ksl = wv & 3, dt = wv >> 2;
    const unsigned short* vrow = vbf + ((size_t)(b * 256 + h * 32 + dt * 16 + m16)) * NTOK;
    const unsigned short* parow = rows[lane & 7].pa;   // A rows 8..15 dup rows 0..7 (C rows 8..15 unused)
    f32x4 acc = {0.f, 0.f, 0.f, 0.f};
    const int nb = ksl * 256;
    #pragma unroll
    for (int ks = 0; ks < 8; ks++) {
      const int n0 = nb + ks * 32 + g * 8;
      bf16x8 a  = __builtin_bit_cast(bf16x8, *(const u16x8*)&parow[n0]);
      bf16x8 b0 = __builtin_bit_cast(bf16x8, *(const u16x8*)&vrow[n0]);
      acc = __builtin_amdgcn_mfma_f32_16x16x32_bf16(a, b0, acc, 0, 0, 0);
    }
    if (g < 2) {
      #pragma unroll
      for (int q = 0; q < 4; q++)
        u.pvred[dt][ksl][g * 4 + q][m16] = acc[q];
    }
  }
  __syncthreads();

  // ---- epilogue: attn result + fused depthwise 3x3 PE conv (fp32) ----
  if (tid < 256) {
    const int r2 = tid & 7, d2 = tid >> 3;
    const int dt = d2 >> 4, m16 = d2 & 15;
    float s = u.pvred[dt][0][r2][m16] + u.pvred[dt][1][r2][m16]
            + u.pvred[dt][2][r2][m16] + u.pvred[dt][3][r2][m16];
    s *= invs[r2];
    // pe: channel c = h*32 + d2, v-image channel in qkv = b*512 + h*64 + 32 + d2
    const int c = h * 32 + d2;
    const float* vimg = qkv + (size_t)(b * 512 + h * 64 + 32 + d2) * NTOK;
    const int p = mb * 8 + r2;
    const int y = p >> 5, x = p & 31;
    float pe = pe_b[c];
    const float* wp = pe_w + c * 9;
    #pragma unroll
    for (int dy = -1; dy <= 1; dy++) {
      const int yy = y + dy;
      if (yy < 0 || yy > 31) continue;
      #pragma unroll
      for (int dx = -1; dx <= 1; dx++) {
        const int xx = x + dx;
        if (xx < 0 || xx > 31) continue;
        pe = fmaf(wp[(dy + 1) * 3 + (dx + 1)], vimg[yy * 32 + xx], pe);
      }
    }
    tmp[(size_t)(b * 256 + c) * NTOK + p] = s + pe;
  }
}

extern "C" void kernel_launch(void* const* d_in, const int* in_sizes, int n_in,
                              void* d_out, int out_size, void* d_ws, size_t ws_size,
                              hipStream_t stream) {
  const float* x      = (const float*)d_in[0];
  const float* qkv_w  = (const float*)d_in[1];
  const float* qkv_b  = (const float*)d_in[2];
  const float* proj_w = (const float*)d_in[3];
  const float* proj_b = (const float*)d_in[4];
  const float* pe_w   = (const float*)d_in[5];
  const float* pe_b   = (const float*)d_in[6];
  const float* g1_w   = (const float*)d_in[7];
  const float* g1_b   = (const float*)d_in[8];
  const float* g2_w   = (const float*)d_in[9];
  const float* g2_b   = (const float*)d_in[10];
  float* out = (float*)d_out;

  char* ws = (char*)d_ws;
  float*  qkvb  = (float*)(ws);                          // 8 MB
  float*  tmp   = (float*)(ws + (8u << 20));             // 4 MB (attn+pe output)
  float*  gx    = (float*)(ws + (12u << 20));            // 2 MB (gate hidden)
  // vbf aliases gx: gx dead after gate2 (stream-ordered before qkv conv writes)
  unsigned short* vbf = (unsigned short*)(ws + (12u << 20));   // 2 MB bf16 V
  double* part  = (double*)(ws + (14u << 20));           // 16 doubles

  // gate path -> partials (dyn_k computed inside attn)
  conv1x1_kernel<128, 4, 2, true, false><<<256, 256, 0, stream>>>(x, g1_w, g1_b, gx, nullptr);
  gate2_kernel<<<16, 256, 0, stream>>>(gx, g2_w, g2_b, part);
  // qkv (+ fused bf16 cast of V channels); overwrites gx region with vbf
  conv1x1_kernel<512, 4, 2, false, true><<<1024, 256, 0, stream>>>(x, qkv_w, qkv_b, qkvb, vbf);
  // attention (exact top-dyn_k masked softmax, MFMA PV, fused PE conv)
  attn_kernel<<<4096, 512, 0, stream>>>(qkvb, vbf, part, pe_w, pe_b, tmp);
  // final projection
  conv1x1_kernel<256, 4, 2, false, false><<<512, 256, 0, stream>>>(tmp, proj_w, proj_b, out, nullptr);
}